// Round 11
// baseline (165.610 us; speedup 1.0000x reference)
//
#include <hip/hip_runtime.h>
#include <hip/hip_bf16.h>

#define CCH 384
#define HW2 3136
#define HH 56
#define WW 56
#define QMAX 7.0f
#define SCALE_MIN 2e-16f
#define YSTR 40          // ysh pos-stride in halves (80 B)

typedef _Float16 half8 __attribute__((ext_vector_type(8)));
typedef float f32x4 __attribute__((ext_vector_type(4)));

// ---------------- quant kernels (Brevitas per-channel symmetric int4) -------

__global__ void quant_dw(const float* __restrict__ dw, float* __restrict__ dwq) {
    int c = blockIdx.x * blockDim.x + threadIdx.x;
    if (c >= CCH) return;
    float w[9];
    float amax = 0.f;
    #pragma unroll
    for (int j = 0; j < 9; ++j) {
        w[j] = dw[c * 9 + j];
        amax = fmaxf(amax, fabsf(w[j]));
    }
    float scale = fmaxf(amax / QMAX, SCALE_MIN);
    #pragma unroll
    for (int j = 0; j < 9; ++j) {
        float q = rintf(w[j] / scale);          // round half-even = jnp.round
        q = fminf(fmaxf(q, -QMAX), QMAX);
        dwq[c * 9 + j] = q * scale;
    }
}

// one block (64 threads) per output channel; fake-quant then pack fp16 into
// MFMA A-fragment layout: wpk[(ci/32)*24 + co/16][lane][8]
__global__ void quant_pw(const float* __restrict__ pw, _Float16* __restrict__ wpk) {
    int co = blockIdx.x;
    int lane = threadIdx.x;
    float w[6];
    float amax = 0.f;
    #pragma unroll
    for (int j = 0; j < 6; ++j) {
        w[j] = pw[co * CCH + lane + j * 64];
        amax = fmaxf(amax, fabsf(w[j]));
    }
    #pragma unroll
    for (int off = 32; off >= 1; off >>= 1)
        amax = fmaxf(amax, __shfl_xor(amax, off));
    float scale = fmaxf(amax / QMAX, SCALE_MIN);
    #pragma unroll
    for (int j = 0; j < 6; ++j) {
        int ci = lane + j * 64;
        float q = rintf(w[j] / scale);
        q = fminf(fmaxf(q, -QMAX), QMAX);
        float v = q * scale;
        int kk  = ci >> 5;
        int cis = ci & 31;
        int l   = (co & 15) | ((cis >> 3) << 4);
        int idx = (kk * 24 + (co >> 4)) * 512 + l * 8 + (cis & 7);
        wpk[idx] = (_Float16)v;
    }
}

// ---------------- fused kernel: dw 3x3 -> LDS y-panel -> MFMA pw ------------
// Block: 256 thr, one (n, output row h0): 56 pos x 384 co. 12 ci-panels of 32.
// computeY: lane=(ci 0..31, seg 0..6): 10 aligned global f32x4 row reads
// (L2-hot; edge quads zeroed, OOB rows uniform-skipped), 72 FMA, y fp16 ->
// ysh[pos][ci] (stride 40 halves). GEMM: r3-proven K-step, wpk layout
// unchanged (kk = panel). y never touches global memory.

__global__ __launch_bounds__(256) void fused_kernel(
    const float* __restrict__ x, const float* __restrict__ dwq,
    const _Float16* __restrict__ wpk, const float* __restrict__ bias,
    float* __restrict__ out)
{
    __shared__ __align__(16) _Float16 ysh[64 * YSTR];   // 5120 B

    int bid = blockIdx.x;                  // 1792 = 8 XCDs * 224, chunked
    int wg = (bid & 7) * 224 + (bid >> 3);
    int n = wg / WW, h0 = wg % WW;

    const int tid  = threadIdx.x;
    const int lane = tid & 63;
    const int g    = __builtin_amdgcn_readfirstlane(tid >> 6);

    // computeY role: 224 active lanes
    const int yci = tid >> 3;              // 0..31 (ci within panel)
    const int s   = tid & 7;               // seg; active if s<7
    const bool act = (s < 7);
    const int w0  = 8 * s;

    // zero the never-written pos rows 56..63 (GEMM reads them; keep them 0)
    if (tid >= 224) {
        int i = tid - 224;                 // 0..31
        f32x4* zb = (f32x4*)((char*)ysh + 56 * 2 * YSTR);
        zb[i] = (f32x4){0.f, 0.f, 0.f, 0.f};
        if (i < 8) zb[32 + i] = (f32x4){0.f, 0.f, 0.f, 0.f};
    }

    const int lco = lane & 15;
    const int lkg = lane >> 4;

    f32x4 acc[6][4];
    #pragma unroll
    for (int mc = 0; mc < 6; ++mc)
        #pragma unroll
        for (int np = 0; np < 4; ++np)
            acc[mc][np] = (f32x4){0.f, 0.f, 0.f, 0.f};

    const float* xn = x + (size_t)n * CCH * HW2;
    const f32x4 z4 = (f32x4){0.f, 0.f, 0.f, 0.f};

    for (int p = 0; p < 12; ++p) {
        // ---- phase 1: depthwise for this ci-panel -> ysh ----
        if (act) {
            const int ci = p * 32 + yci;
            const float* xc = xn + (size_t)ci * HW2;
            const float* wqp = dwq + ci * 9;
            float wv[9];
            #pragma unroll
            for (int k = 0; k < 9; ++k) wv[k] = wqp[k];

            float a[8] = {0.f,0.f,0.f,0.f,0.f,0.f,0.f,0.f};
            #pragma unroll
            for (int dr = 0; dr < 3; ++dr) {
                const int srow = h0 - 1 + dr;
                f32x4 q0, q1, q2, q3;
                if ((unsigned)srow < (unsigned)HH) {      // block-uniform
                    const float* rp = xc + srow * WW;
                    const float* a0 = rp + (s == 0 ? 0 : w0 - 4);
                    const float* a3 = rp + (s == 6 ? w0 + 4 : w0 + 8);
                    q0 = *(const f32x4*)a0;
                    q1 = *(const f32x4*)(rp + w0);
                    q2 = *(const f32x4*)(rp + w0 + 4);
                    q3 = *(const f32x4*)a3;
                    if (s == 0) q0 = z4;
                    if (s == 6) q3 = z4;
                } else {
                    q0 = z4; q1 = z4; q2 = z4; q3 = z4;
                }
                float win[16] = {q0.x,q0.y,q0.z,q0.w, q1.x,q1.y,q1.z,q1.w,
                                 q2.x,q2.y,q2.z,q2.w, q3.x,q3.y,q3.z,q3.w};
                // win[i] = x col (w0-4+i); out col w0+j0 taps win[3+j0..5+j0]
                #pragma unroll
                for (int j0 = 0; j0 < 8; ++j0) {
                    float s0 = a[j0];
                    s0 = fmaf(win[3 + j0], wv[dr * 3 + 0], s0);
                    s0 = fmaf(win[4 + j0], wv[dr * 3 + 1], s0);
                    s0 = fmaf(win[5 + j0], wv[dr * 3 + 2], s0);
                    a[j0] = s0;
                }
            }
            #pragma unroll
            for (int j0 = 0; j0 < 8; ++j0)
                ysh[(w0 + j0) * YSTR + yci] = (_Float16)a[j0];
        }
        __syncthreads();

        // ---- phase 2: GEMM K-step (K=32), r3-proven ----
        half8 wf[6];
        #pragma unroll
        for (int mc = 0; mc < 6; ++mc)
            wf[mc] = *(const half8*)(wpk + (size_t)(p * 24 + g * 6 + mc) * 512 + lane * 8);
        half8 yf[4];
        #pragma unroll
        for (int np = 0; np < 4; ++np)
            yf[np] = *(const half8*)(ysh + (np * 16 + lco) * YSTR + lkg * 8);
        #pragma unroll
        for (int mc = 0; mc < 6; ++mc)
            #pragma unroll
            for (int np = 0; np < 4; ++np)
                acc[mc][np] = __builtin_amdgcn_mfma_f32_16x16x32_f16(
                    wf[mc], yf[np], acc[mc][np], 0, 0, 0);
        __syncthreads();   // before next panel overwrites ysh
    }

    // ---- epilogue: bias + store (row h0, pos<56 guard) ----
    float* ob = out + (size_t)n * CCH * HW2 + h0 * WW;
    #pragma unroll
    for (int mc = 0; mc < 6; ++mc) {
        #pragma unroll
        for (int r = 0; r < 4; ++r) {
            const int co = g * 96 + mc * 16 + lkg * 4 + r;
            const float bv = bias[co];
            #pragma unroll
            for (int np = 0; np < 4; ++np) {
                const int pos = np * 16 + lco;
                if (np < 3 || lco < 8)
                    ob[(size_t)co * HW2 + pos] = acc[mc][np][r] + bv;
            }
        }
    }
}

// ---------------------------------------------------------------------------

extern "C" void kernel_launch(void* const* d_in, const int* in_sizes, int n_in,
                              void* d_out, int out_size, void* d_ws, size_t ws_size,
                              hipStream_t stream) {
    const float* x  = (const float*)d_in[0];
    const float* dw = (const float*)d_in[1];
    const float* pw = (const float*)d_in[2];
    const float* pb = (const float*)d_in[3];
    float* out = (float*)d_out;

    float*    dwq = (float*)d_ws;                         // 3456 f32
    _Float16* wpk = (_Float16*)(dwq + CCH * 9);           // 147456 fp16

    quant_dw<<<2, 256, 0, stream>>>(dw, dwq);
    quant_pw<<<CCH, 64, 0, stream>>>(pw, wpk);

    fused_kernel<<<1792, 256, 0, stream>>>(x, dwq, wpk, pb, out);
}